// Round 15
// baseline (212.015 us; speedup 1.0000x reference)
//
#include <hip/hip_runtime.h>

// ---------------------------------------------------------------------------
// SelfAttention: qkv = X@W + b ; per-head softmax(q k^T * sqrt(64)) @ v
// fp32 in/out. Precision: split-bf16 3-pass MFMA for QK projection and
// Q*K^T (logit sigma ~1e-3), 1-pass bf16 for V projection, fp32 softmax
// (exp2 domain), bf16 PV.
// v15: Vt stored FRAGMENT-MAJOR (8 x 1KB lane-ordered records per tile) so
// attn reads each PV B-fragment as ONE coalesced 1KB wave load from L2
// (fixes v11's per-lane scatter). V leaves LDS: attn LDS traffic -33%
// (204->136 KB/block-tile), LDS 48->32 KB. V loads issued BEFORE the K gl16
// prefetch so their wait is a counted vmcnt. proj/prep = v14.
// ---------------------------------------------------------------------------

#define S_LEN 2048
#define NH    16
#define DH    64
#define DM    1024
#define EW    3072   // NH*(64+64+64)
#define NROWS 4096   // B*S
#define NT    32     // KV tiles of 64 keys

// 8 * log2(e): folds the sqrt(64) score scale AND the exp->exp2 conversion
#define QSCALE 11.5415603f

using f32x4 = __attribute__((ext_vector_type(4))) float;
using bf8   = __attribute__((ext_vector_type(8))) short;   // 8 bf16 (4 VGPRs)
using s4v   = __attribute__((ext_vector_type(4))) short;

static __device__ __forceinline__ short f2bf(float f) {
  union { float f; unsigned u; } a; a.f = f;
  unsigned r = a.u + 0x7fffu + ((a.u >> 16) & 1u);   // RNE
  return (short)(r >> 16);
}
static __device__ __forceinline__ float bf2f(short h) {
  union { float f; unsigned u; } a;
  a.u = ((unsigned)(unsigned short)h) << 16;
  return a.f;
}
static __device__ __forceinline__ void gl16(const void* g, void* l) {
  __builtin_amdgcn_global_load_lds(
      (const __attribute__((address_space(1))) void*)g,
      (__attribute__((address_space(3))) void*)l, 16, 0, 0);
}

// ------------- merged prep: X split (blocks 0..4095) + W transform ----------
// W -> fragment-major W^T, split hi/lo, cols permuted [Q|K|V] (blocks 4096+).
__global__ __launch_bounds__(256) void prep(
    const float* __restrict__ X, const float* __restrict__ W,
    short* __restrict__ Xh, short* __restrict__ Xl,
    short* __restrict__ Wfh, short* __restrict__ Wfl) {
  __shared__ float t[32][33];
  const int id = blockIdx.x;
  if (id < 4096) {
    int i = id * 256 + threadIdx.x;              // 1,048,576 float4s
    float4 v = ((const float4*)X)[i];
    s4v h, l;
    h.x = f2bf(v.x); l.x = f2bf(v.x - bf2f(h.x));
    h.y = f2bf(v.y); l.y = f2bf(v.y - bf2f(h.y));
    h.z = f2bf(v.z); l.z = f2bf(v.z - bf2f(h.z));
    h.w = f2bf(v.w); l.w = f2bf(v.w - bf2f(h.w));
    ((s4v*)Xh)[i] = h;
    ((s4v*)Xl)[i] = l;
  } else {
    const int wid = id - 4096;                   // 0..3071
    int n0 = (wid % 96) * 32;
    int k0 = (wid / 96) * 32;
    int tx = threadIdx.x & 31;
    int ty = threadIdx.x >> 5;        // 0..7
#pragma unroll
    for (int i = 0; i < 32; i += 8)
      t[ty + i][tx] = W[(size_t)(k0 + ty + i) * EW + n0 + tx];
    __syncthreads();
    const int kt = k0 >> 5;
#pragma unroll
    for (int i = 0; i < 32; i += 8) {
      float v = t[tx][ty + i];        // k = k0+tx, n = n0+ty+i (original col)
      int n = n0 + ty + i;
      int h = n / 192, e = n - h * 192;
      int np = (e < 64) ? (h * 64 + e)
             : (e < 128) ? (1024 + h * 64 + (e - 64))
                         : (2048 + h * 64 + (e - 128));
      int n16 = np >> 4, c = np & 15;
      int gg = (tx >> 3) & 3, ee = tx & 7;
      size_t o = ((size_t)(n16 * 32 + kt)) * 512 + (gg * 16 + c) * 8 + ee;
      short hi = f2bf(v);
      Wfh[o] = hi;
      if (np < 2048) Wfl[o] = f2bf(v - bf2f(hi));   // lo only needed for Q,K
    }
  }
}

// ----------------------- merged projection GEMM -----------------------------
// blocks 0..511: QK cols (split-bf16 3-pass); 512..767: V cols (1-pass,
// epilogue writes Vt in attn's fragment-major layout). 1x4 wave split, A in
// dbuf LDS via global_load_lds, B-frags direct from fragment-major global W.
__global__ __launch_bounds__(256, 3) void proj(
    const short* __restrict__ Xh, const short* __restrict__ Xl,
    const short* __restrict__ Wfh, const short* __restrict__ Wfl,
    const float* __restrict__ bias,
    short* __restrict__ Qh, short* __restrict__ Ql,
    short* __restrict__ Kh, short* __restrict__ Kl,
    short* __restrict__ Vt) {
  __shared__ short Ah[2][4096], Al[2][4096];   // 32KB (V path uses Ah only)
  const int tid = threadIdx.x;
  const int lane = tid & 63, w = tid >> 6;
  const int c = lane & 15, g = lane >> 4;

  const int sr  = 32 * w + (lane >> 2);
  const int csw = ((lane & 3) ^ ((lane >> 3) & 3)) * 8;   // shorts
  const int ldsw = w * 1024;                              // shorts, seg base
  const int rsw = (g ^ ((c >> 1) & 3)) * 8;               // read-side swizzle

  if (blockIdx.x < 512) {
    // ---------------- QK path ----------------
    const int id = blockIdx.x;                  // 0..511
    const int t = id >> 3;                      // 0..63
    const int rowBase = (((id & 7) << 2) + (t & 3)) * 128;
    const int colBase = (t >> 2) * 128;         // 0..1920 (permuted cols)

    f32x4 acc[8][2] = {};
    const size_t aBase = (size_t)(rowBase + sr) * DM + csw;

    size_t bB[2];
#pragma unroll
    for (int n = 0; n < 2; ++n)
      bB[n] = ((size_t)((colBase >> 4) + w * 2 + n) * 32) * 512 + lane * 8;

#define ASTAGE(B, kt) do {                                    \
    gl16(&Xh[aBase + (kt)],            &Ah[B][ldsw]);         \
    gl16(&Xh[aBase + (kt) + 16 * DM],  &Ah[B][ldsw + 512]);   \
    gl16(&Xl[aBase + (kt)],            &Al[B][ldsw]);         \
    gl16(&Xl[aBase + (kt) + 16 * DM],  &Al[B][ldsw + 512]);   \
  } while (0)
#define LOADB(dh, dl, kt) do {                                \
    _Pragma("unroll")                                         \
    for (int n = 0; n < 2; ++n) {                             \
      dh[n] = *(const bf8*)&Wfh[bB[n] + (size_t)(kt) * 512];  \
      dl[n] = *(const bf8*)&Wfl[bB[n] + (size_t)(kt) * 512];  \
    }                                                         \
  } while (0)
#define QKHALF(B, h0, bh, bl) do {                            \
    bf8 ah[4], al4[4];                                        \
    _Pragma("unroll")                                         \
    for (int mm = 0; mm < 4; ++mm) {                          \
      int ro = (((h0) + mm) * 16 + c) * 32 + rsw;             \
      ah[mm]  = *(const bf8*)&Ah[B][ro];                      \
      al4[mm] = *(const bf8*)&Al[B][ro];                      \
    }                                                         \
    __builtin_amdgcn_s_setprio(1);                            \
    _Pragma("unroll")                                         \
    for (int mm = 0; mm < 4; ++mm) {                          \
      _Pragma("unroll")                                       \
      for (int n = 0; n < 2; ++n) {                           \
        acc[(h0) + mm][n] = __builtin_amdgcn_mfma_f32_16x16x32_bf16(al4[mm], bh[n], acc[(h0) + mm][n], 0, 0, 0); \
        acc[(h0) + mm][n] = __builtin_amdgcn_mfma_f32_16x16x32_bf16(ah[mm], bl[n], acc[(h0) + mm][n], 0, 0, 0);  \
        acc[(h0) + mm][n] = __builtin_amdgcn_mfma_f32_16x16x32_bf16(ah[mm], bh[n], acc[(h0) + mm][n], 0, 0, 0);  \
      }                                                       \
    }                                                         \
    __builtin_amdgcn_s_setprio(0);                            \
  } while (0)

    bf8 b0h[2], b0l[2], b1h[2], b1l[2];
    LOADB(b0h, b0l, 0);
    ASTAGE(0, 0);
    __syncthreads();

    for (int it = 0; it < 32; it += 2) {
      LOADB(b1h, b1l, it + 1);
      ASTAGE(1, (it + 1) * 32);
      QKHALF(0, 0, b0h, b0l);
      QKHALF(0, 4, b0h, b0l);
      __syncthreads();

      if (it + 2 < 32) {
        LOADB(b0h, b0l, it + 2);
        ASTAGE(0, (it + 2) * 32);
      }
      QKHALF(1, 0, b1h, b1l);
      QKHALF(1, 4, b1h, b1l);
      __syncthreads();
    }
#undef ASTAGE
#undef LOADB
#undef QKHALF

#pragma unroll
    for (int m = 0; m < 8; ++m)
#pragma unroll
      for (int n = 0; n < 2; ++n)
#pragma unroll
        for (int j = 0; j < 4; ++j) {
          int grow = rowBase + m * 16 + g * 4 + j;             // 0..4095
          int gcol = colBase + w * 32 + n * 16 + c;            // 0..2047
          int h = (gcol >> 6) & 15, e = gcol & 63;
          int bb = grow >> 11, s = grow & 2047;
          size_t hb = (size_t)(bb * NH + h);
          if (gcol < 1024) {                 // Q: orig col h*192+e
            float q8 = (acc[m][n][j] + bias[h * 192 + e]) * QSCALE;
            short hi = f2bf(q8);
            short lo = f2bf(q8 - bf2f(hi));
            size_t idx = (hb * S_LEN + s) * DH + e;
            Qh[idx] = hi; Ql[idx] = lo;
          } else {                           // K: orig col h*192+64+e
            float v = acc[m][n][j] + bias[h * 192 + 64 + e];
            short hi = f2bf(v);
            short lo = f2bf(v - bf2f(hi));
            int tile = s >> 6, r = s & 63;
            size_t idx = ((hb * NT + tile) * (size_t)4096) + r * 64 +
                         ((((e >> 3) ^ (r & 7)) << 3) | (e & 7));
            Kh[idx] = hi; Kl[idx] = lo;
          }
        }
  } else {
    // ---------------- V path (1-pass) ----------------
    const int id = blockIdx.x - 512;            // 0..255
    const int t = id >> 3;                      // 0..31
    const int rowBase = (((id & 7) << 2) + (t & 3)) * 128;
    const int colBase = 2048 + (t >> 2) * 128;  // permuted V region

    f32x4 acc[8][2] = {};
    const size_t aBase = (size_t)(rowBase + sr) * DM + csw;

    size_t bB[2];
#pragma unroll
    for (int n = 0; n < 2; ++n)
      bB[n] = ((size_t)((colBase >> 4) + w * 2 + n) * 32) * 512 + lane * 8;

#define VASTAGE(B, kt) do {                                   \
    gl16(&Xh[aBase + (kt)],            &Ah[B][ldsw]);         \
    gl16(&Xh[aBase + (kt) + 16 * DM],  &Ah[B][ldsw + 512]);   \
  } while (0)
#define VLOADB(dh, kt) do {                                   \
    _Pragma("unroll")                                         \
    for (int n = 0; n < 2; ++n)                               \
      dh[n] = *(const bf8*)&Wfh[bB[n] + (size_t)(kt) * 512];  \
  } while (0)
#define VHALF(B, h0, bh) do {                                 \
    bf8 ah[4];                                                \
    _Pragma("unroll")                                         \
    for (int mm = 0; mm < 4; ++mm)                            \
      ah[mm] = *(const bf8*)&Ah[B][(((h0) + mm) * 16 + c) * 32 + rsw]; \
    __builtin_amdgcn_s_setprio(1);                            \
    _Pragma("unroll")                                         \
    for (int mm = 0; mm < 4; ++mm) {                          \
      _Pragma("unroll")                                       \
      for (int n = 0; n < 2; ++n)                             \
        acc[(h0) + mm][n] = __builtin_amdgcn_mfma_f32_16x16x32_bf16(ah[mm], bh[n], acc[(h0) + mm][n], 0, 0, 0); \
    }                                                         \
    __builtin_amdgcn_s_setprio(0);                            \
  } while (0)

    bf8 b0h[2], b1h[2];
    VLOADB(b0h, 0);
    VASTAGE(0, 0);
    __syncthreads();

    for (int it = 0; it < 32; it += 2) {
      VLOADB(b1h, it + 1);
      VASTAGE(1, (it + 1) * 32);
      VHALF(0, 0, b0h);
      VHALF(0, 4, b0h);
      __syncthreads();

      if (it + 2 < 32) {
        VLOADB(b0h, it + 2);
        VASTAGE(0, (it + 2) * 32);
      }
      VHALF(1, 0, b1h);
      VHALF(1, 4, b1h);
      __syncthreads();
    }
#undef VASTAGE
#undef VLOADB
#undef VHALF

    // epilogue: V -> fragment-major tiles: record fid=(kc*4+db) of 1KB,
    // lane (g4,c) element ii; attn reads each fragment as ONE coalesced
    // 1KB wave load at fid*512 + lane*8.
#pragma unroll
    for (int m = 0; m < 8; ++m)
#pragma unroll
      for (int n = 0; n < 2; ++n)
#pragma unroll
        for (int j = 0; j < 4; ++j) {
          int grow = rowBase + m * 16 + g * 4 + j;
          int gcol = colBase + w * 32 + n * 16 + c;          // 2048..3071
          int h = (gcol >> 6) & 15, d = gcol & 63;
          int bb = grow >> 11, s = grow & 2047;
          size_t hb = (size_t)(bb * NH + h);
          float v = acc[m][n][j] + bias[h * 192 + 128 + d];
          int tile = s >> 6, key = s & 63;
          int kc = key >> 5, g4 = (key >> 2) & 3;
          int ii = (((key >> 4) & 1) << 2) | (key & 3);
          int fid = (kc << 2) | (d >> 4);
          size_t idx = ((hb * NT + tile) * (size_t)4096) + fid * 512 +
                       (g4 * 16 + (d & 15)) * 8 + ii;
          Vt[idx] = f2bf(v);
        }
  }
}

// ------------------------------ attention -----------------------------------
// 512 blocks (XCD-swizzled), 8 waves x 16 q-rows share one bh. Swapped QK^T
// with -mrun folded into the MFMA C-init; in-lane max; lsum via MFMA ones-
// column; cvt_pk P-pack. K hi/lo LDS-dbuf via global_load_lds; V fragments
// read DIRECT from fragment-major global Vt (one coalesced 1KB wave load
// each, L2-resident), issued BEFORE the K prefetch. ONE barrier per tile.
__global__ __launch_bounds__(512, 4) void attn(
    const short* __restrict__ Qh, const short* __restrict__ Ql,
    const short* __restrict__ KhG, const short* __restrict__ KlG,
    const short* __restrict__ VtG, float* __restrict__ out) {
  __shared__ short KHs[2][4096];   // 16 KB
  __shared__ short KLs[2][4096];   // 16 KB

  const int tid = threadIdx.x;
  const int lane = tid & 63, w = tid >> 6;     // 8 waves
  const int c = lane & 15, g = lane >> 4;
  const int id = blockIdx.x;                   // 0..511
  const int lid = (id & 7) * 64 + (id >> 3);   // 64 consecutive per XCD
  const int bh = lid >> 4;
  const int q0 = (lid & 15) * 128 + w * 16;
  const size_t qBase  = (size_t)bh * S_LEN * DH;
  const size_t kvBase = (size_t)bh * NT * 4096;

  const int seg = tid * 8;     // one 16B chunk per thread per K buffer
  const int vlo = lane * 8;    // lane offset within a V fragment record

  // q fragments (hi/lo), rows q0+c — used as the MFMA B operand
  bf8 qh[2], ql[2];
#pragma unroll
  for (int kc = 0; kc < 2; ++kc) {
    size_t idx = qBase + (size_t)(q0 + c) * DH + kc * 32 + g * 8;
    qh[kc] = *(const bf8*)&Qh[idx];
    ql[kc] = *(const bf8*)&Ql[idx];
  }

  // t-invariant swizzled K fragment offsets ((i*16+c)&7 == c&7)
  int koff[2][4];
#pragma unroll
  for (int kc = 0; kc < 2; ++kc)
#pragma unroll
    for (int i = 0; i < 4; ++i)
      koff[kc][i] = (i * 16 + c) * 64 + (((kc * 4 + g) ^ (c & 7)) << 3);

  f32x4 mneg = {0.f, 0.f, 0.f, 0.f};   // all elems = -mrun (q-row c)
  f32x4 osum = {};                     // osum[j] = lsum of q-row 4g+j
  f32x4 o[4] = {};                     // o[db][j]: row 4g+j, d = db*16+c
  union { bf8 v; unsigned u[4]; } ones;
  ones.u[0] = ones.u[1] = ones.u[2] = ones.u[3] = 0x3F803F80u;  // bf16 1.0 x8

  // prologue: stage K tile 0
  gl16(&KhG[kvBase + seg], &KHs[0][seg]);
  gl16(&KlG[kvBase + seg], &KLs[0][seg]);
  __syncthreads();

  for (int t = 0; t < NT; ++t) {
    const int cur = t & 1, nxt = cur ^ 1;
    const size_t vtb = kvBase + (size_t)t * 4096 + vlo;

    // V fragments for THIS tile: coalesced 1KB wave loads from L2, issued
    // first so their wait is a counted vmcnt (K prefetch stays in flight).
    bf8 vb[2][4];
#pragma unroll
    for (int kc = 0; kc < 2; ++kc)
#pragma unroll
      for (int db = 0; db < 4; ++db)
        vb[kc][db] = *(const bf8*)&VtG[vtb + ((kc << 2) | db) * 512];

    if (t + 1 < NT) {                    // K DMA for next tile
      size_t tb = kvBase + (size_t)(t + 1) * 4096 + seg;
      gl16(&KhG[tb], &KHs[nxt][seg]);
      gl16(&KlG[tb], &KLs[nxt][seg]);
    }
    const short* KH = &KHs[cur][0];
    const short* KL = &KLs[cur][0];

    // scores, swapped: sc[nb][j] = S[key=16nb+4g+j][q-row c] - mrun
    f32x4 sc[4];
    __builtin_amdgcn_s_setprio(1);
#pragma unroll
    for (int nb = 0; nb < 4; ++nb) {
      bf8 kh0 = *(const bf8*)&KH[koff[0][nb]];
      bf8 kl0 = *(const bf8*)&KL[koff[0][nb]];
      f32x4 s = __builtin_amdgcn_mfma_f32_16x16x32_bf16(kh0, ql[0], mneg, 0, 0, 0);
      s = __builtin_amdgcn_mfma_f32_16x16x32_bf16(kl0, qh[0], s, 0, 0, 0);
      s = __builtin_amdgcn_mfma_f32_16x16x32_bf16(kh0, qh[0], s, 0, 0, 0);
      bf8 kh1 = *(const bf8*)&KH[koff[1][nb]];
      bf8 kl1 = *(const bf8*)&KL[koff[1][nb]];
      s = __builtin_amdgcn_mfma_f32_16x16x32_bf16(kh1, ql[1], s, 0, 0, 0);
      s = __builtin_amdgcn_mfma_f32_16x16x32_bf16(kl1, qh[1], s, 0, 0, 0);
      s = __builtin_amdgcn_mfma_f32_16x16x32_bf16(kh1, qh[1], s, 0, 0, 0);
      sc[nb] = s;
    }
    __builtin_amdgcn_s_setprio(0);

    // in-lane row max, then across the 4 g-copies
    float m0 = fmaxf(fmaxf(sc[0][0], sc[0][1]), sc[0][2]);
    m0 = fmaxf(fmaxf(m0, sc[0][3]), sc[1][0]);
    m0 = fmaxf(fmaxf(m0, sc[1][1]), sc[1][2]);
    m0 = fmaxf(fmaxf(m0, sc[1][3]), sc[2][0]);
    m0 = fmaxf(fmaxf(m0, sc[2][1]), sc[2][2]);
    m0 = fmaxf(fmaxf(m0, sc[2][3]), sc[3][0]);
    m0 = fmaxf(fmaxf(m0, sc[3][1]), sc[3][2]);
    m0 = fmaxf(m0, sc[3][3]);
    m0 = fmaxf(m0, __shfl_xor(m0, 16));
    m0 = fmaxf(m0, __shfl_xor(m0, 32));

    if (__any(m0 > 8.0f)) {              // defer-max: p bounded by 2^8
      float delta = fmaxf(m0, 0.0f);
      float scale = exp2f(-delta);
      int sb = (g << 4) | (g << 2);
      float s0 = __shfl(scale, sb);
      float s1 = __shfl(scale, sb + 1);
      float s2 = __shfl(scale, sb + 2);
      float s3 = __shfl(scale, sb + 3);
#pragma unroll
      for (int db = 0; db < 4; ++db) {
        o[db][0] *= s0; o[db][1] *= s1; o[db][2] *= s2; o[db][3] *= s3;
      }
      osum[0] *= s0; osum[1] *= s1; osum[2] *= s2; osum[3] *= s3;
      mneg[0] -= delta; mneg[1] -= delta; mneg[2] -= delta; mneg[3] -= delta;
#pragma unroll
      for (int nb = 0; nb < 4; ++nb)
#pragma unroll
        for (int j = 0; j < 4; ++j)
          sc[nb][j] = exp2f(sc[nb][j] - delta);
    } else {
#pragma unroll
      for (int nb = 0; nb < 4; ++nb)
#pragma unroll
        for (int j = 0; j < 4; ++j)
          sc[nb][j] = exp2f(sc[nb][j]);
    }

    // pack p into PV A-fragments (cvt_pk)
    union { bf8 v; unsigned u[4]; } pa[2];
#pragma unroll
    for (int kc = 0; kc < 2; ++kc) {
      asm("v_cvt_pk_bf16_f32 %0, %1, %2"
          : "=v"(pa[kc].u[0]) : "v"(sc[2 * kc][0]), "v"(sc[2 * kc][1]));
      asm("v_cvt_pk_bf16_f32 %0, %1, %2"
          : "=v"(pa[kc].u[1]) : "v"(sc[2 * kc][2]), "v"(sc[2 * kc][3]));
      asm("v_cvt_pk_bf16_f32 %0, %1, %2"
          : "=v"(pa[kc].u[2]) : "v"(sc[2 * kc + 1][0]), "v"(sc[2 * kc + 1][1]));
      asm("v_cvt_pk_bf16_f32 %0, %1, %2"
          : "=v"(pa[kc].u[3]) : "v"(sc[2 * kc + 1][2]), "v"(sc[2 * kc + 1][3]));
    }

    // PV + lsum: B = V fragment (regs, key-permuted) and ones column
    __builtin_amdgcn_s_setprio(1);
#pragma unroll
    for (int kc = 0; kc < 2; ++kc) {
      osum = __builtin_amdgcn_mfma_f32_16x16x32_bf16(pa[kc].v, ones.v, osum, 0, 0, 0);
#pragma unroll
      for (int db = 0; db < 4; ++db)
        o[db] = __builtin_amdgcn_mfma_f32_16x16x32_bf16(pa[kc].v, vb[kc][db], o[db], 0, 0, 0);
    }
    __builtin_amdgcn_s_setprio(0);

    __syncthreads();   // drains vmcnt (next K tile staged) + cur reads done
  }

  // final: lsum is lane-local in osum[j]
  float r0 = 1.f / osum[0];
  float r1 = 1.f / osum[1];
  float r2 = 1.f / osum[2];
  float r3 = 1.f / osum[3];

  const int b = bh >> 4, h = bh & 15;
#pragma unroll
  for (int db = 0; db < 4; ++db) {
    int col = h * DH + db * 16 + c;
    out[((size_t)b * S_LEN + q0 + g * 4 + 0) * DM + col] = o[db][0] * r0;
    out[((size_t)b * S_LEN + q0 + g * 4 + 1) * DM + col] = o[db][1] * r1;
    out[((size_t)b * S_LEN + q0 + g * 4 + 2) * DM + col] = o[db][2] * r2;
    out[((size_t)b * S_LEN + q0 + g * 4 + 3) * DM + col] = o[db][3] * r3;
  }
}

// ---------------------------------------------------------------------------
extern "C" void kernel_launch(void* const* d_in, const int* in_sizes, int n_in,
                              void* d_out, int out_size, void* d_ws, size_t ws_size,
                              hipStream_t stream) {
  const float* X    = (const float*)d_in[0];
  const float* W    = (const float*)d_in[1];
  const float* bias = (const float*)d_in[2];
  float* out = (float*)d_out;

  char* ws = (char*)d_ws;
  size_t off = 0;
  auto take = [&](size_t bytes) {
    void* p = ws + off;
    off += (bytes + 255) & ~(size_t)255;
    return p;
  };
  short* Xh  = (short*)take((size_t)NROWS * DM * 2);   // 8.4 MB
  short* Xl  = (short*)take((size_t)NROWS * DM * 2);
  short* Wfh = (short*)take((size_t)EW * DM * 2);      // 6.3 MB
  short* Wfl = (short*)take((size_t)EW * DM * 2);
  short* Qh  = (short*)take((size_t)2 * NH * S_LEN * DH * 2);  // 8.4 MB each
  short* Ql  = (short*)take((size_t)2 * NH * S_LEN * DH * 2);
  short* Kh  = (short*)take((size_t)2 * NH * NT * 4096 * 2);
  short* Kl  = (short*)take((size_t)2 * NH * NT * 4096 * 2);
  short* Vt  = (short*)take((size_t)2 * NH * NT * 4096 * 2);
  // total ~71.3 MB of workspace

  prep<<<dim3(4096 + 3072), dim3(256), 0, stream>>>(X, W, Xh, Xl, Wfh, Wfl);
  proj<<<dim3(768), dim3(256), 0, stream>>>(
      Xh, Xl, Wfh, Wfl, bias, Qh, Ql, Kh, Kl, Vt);
  attn<<<dim3(512), dim3(512), 0, stream>>>(
      Qh, Ql, Kh, Kl, Vt, out);
}

// Round 16
// 159.077 us; speedup vs baseline: 1.3328x; 1.3328x over previous
//
#include <hip/hip_runtime.h>

// ---------------------------------------------------------------------------
// SelfAttention: qkv = X@W + b ; per-head softmax(q k^T * sqrt(64)) @ v
// fp32 in/out. Precision: split-bf16 3-pass MFMA for QK projection and
// Q*K^T (logit sigma ~1e-3), 1-pass bf16 for V projection, fp32 softmax
// (exp2 domain), bf16 PV.
// v16 = v14 exact revert (best measured 159.2us). v15's V-direct regressed:
// a 1KB coalesced global wave-load costs ~16cyc of the CU TA port vs ~12cyc
// ds_read_b128, plus 8x per-wave L2 duplication that block-level LDS DMA
// amortized. attn v10 structure is the verified local optimum.
// ---------------------------------------------------------------------------

#define S_LEN 2048
#define NH    16
#define DH    64
#define DM    1024
#define EW    3072   // NH*(64+64+64)
#define NROWS 4096   // B*S
#define NT    32     // KV tiles of 64 keys

// 8 * log2(e): folds the sqrt(64) score scale AND the exp->exp2 conversion
#define QSCALE 11.5415603f

using f32x4 = __attribute__((ext_vector_type(4))) float;
using bf8   = __attribute__((ext_vector_type(8))) short;   // 8 bf16 (4 VGPRs)
using s4v   = __attribute__((ext_vector_type(4))) short;

static __device__ __forceinline__ short f2bf(float f) {
  union { float f; unsigned u; } a; a.f = f;
  unsigned r = a.u + 0x7fffu + ((a.u >> 16) & 1u);   // RNE
  return (short)(r >> 16);
}
static __device__ __forceinline__ float bf2f(short h) {
  union { float f; unsigned u; } a;
  a.u = ((unsigned)(unsigned short)h) << 16;
  return a.f;
}
static __device__ __forceinline__ void gl16(const void* g, void* l) {
  __builtin_amdgcn_global_load_lds(
      (const __attribute__((address_space(1))) void*)g,
      (__attribute__((address_space(3))) void*)l, 16, 0, 0);
}

// ------------- merged prep: X split (blocks 0..4095) + W transform ----------
// W -> fragment-major W^T, split hi/lo, cols permuted [Q|K|V] (blocks 4096+).
__global__ __launch_bounds__(256) void prep(
    const float* __restrict__ X, const float* __restrict__ W,
    short* __restrict__ Xh, short* __restrict__ Xl,
    short* __restrict__ Wfh, short* __restrict__ Wfl) {
  __shared__ float t[32][33];
  const int id = blockIdx.x;
  if (id < 4096) {
    int i = id * 256 + threadIdx.x;              // 1,048,576 float4s
    float4 v = ((const float4*)X)[i];
    s4v h, l;
    h.x = f2bf(v.x); l.x = f2bf(v.x - bf2f(h.x));
    h.y = f2bf(v.y); l.y = f2bf(v.y - bf2f(h.y));
    h.z = f2bf(v.z); l.z = f2bf(v.z - bf2f(h.z));
    h.w = f2bf(v.w); l.w = f2bf(v.w - bf2f(h.w));
    ((s4v*)Xh)[i] = h;
    ((s4v*)Xl)[i] = l;
  } else {
    const int wid = id - 4096;                   // 0..3071
    int n0 = (wid % 96) * 32;
    int k0 = (wid / 96) * 32;
    int tx = threadIdx.x & 31;
    int ty = threadIdx.x >> 5;        // 0..7
#pragma unroll
    for (int i = 0; i < 32; i += 8)
      t[ty + i][tx] = W[(size_t)(k0 + ty + i) * EW + n0 + tx];
    __syncthreads();
    const int kt = k0 >> 5;
#pragma unroll
    for (int i = 0; i < 32; i += 8) {
      float v = t[tx][ty + i];        // k = k0+tx, n = n0+ty+i (original col)
      int n = n0 + ty + i;
      int h = n / 192, e = n - h * 192;
      int np = (e < 64) ? (h * 64 + e)
             : (e < 128) ? (1024 + h * 64 + (e - 64))
                         : (2048 + h * 64 + (e - 128));
      int n16 = np >> 4, c = np & 15;
      int gg = (tx >> 3) & 3, ee = tx & 7;
      size_t o = ((size_t)(n16 * 32 + kt)) * 512 + (gg * 16 + c) * 8 + ee;
      short hi = f2bf(v);
      Wfh[o] = hi;
      if (np < 2048) Wfl[o] = f2bf(v - bf2f(hi));   // lo only needed for Q,K
    }
  }
}

// ----------------------- merged projection GEMM -----------------------------
// blocks 0..511: QK cols (split-bf16 3-pass); 512..767: V cols (1-pass).
// 1x4 wave split: wave w computes rows 0..127 x cols [w*32, w*32+32) -> B
// fragments disjoint across waves (no duplicated L2 loads). A staged in dbuf
// LDS via global_load_lds; B-frags direct from fragment-major global W,
// 1-step register prefetch; A-frag reads in two 4-row halves.
__global__ __launch_bounds__(256, 3) void proj(
    const short* __restrict__ Xh, const short* __restrict__ Xl,
    const short* __restrict__ Wfh, const short* __restrict__ Wfl,
    const float* __restrict__ bias,
    short* __restrict__ Qh, short* __restrict__ Ql,
    short* __restrict__ Kh, short* __restrict__ Kl,
    short* __restrict__ Vt) {
  __shared__ short Ah[2][4096], Al[2][4096];   // 32KB (V path uses Ah only)
  const int tid = threadIdx.x;
  const int lane = tid & 63, w = tid >> 6;
  const int c = lane & 15, g = lane >> 4;

  const int sr  = 32 * w + (lane >> 2);
  const int csw = ((lane & 3) ^ ((lane >> 3) & 3)) * 8;   // shorts
  const int ldsw = w * 1024;                              // shorts, seg base
  const int rsw = (g ^ ((c >> 1) & 3)) * 8;               // read-side swizzle

  if (blockIdx.x < 512) {
    // ---------------- QK path ----------------
    const int id = blockIdx.x;                  // 0..511
    const int t = id >> 3;                      // 0..63
    const int rowBase = (((id & 7) << 2) + (t & 3)) * 128;
    const int colBase = (t >> 2) * 128;         // 0..1920 (permuted cols)

    f32x4 acc[8][2] = {};
    const size_t aBase = (size_t)(rowBase + sr) * DM + csw;

    size_t bB[2];
#pragma unroll
    for (int n = 0; n < 2; ++n)
      bB[n] = ((size_t)((colBase >> 4) + w * 2 + n) * 32) * 512 + lane * 8;

#define ASTAGE(B, kt) do {                                    \
    gl16(&Xh[aBase + (kt)],            &Ah[B][ldsw]);         \
    gl16(&Xh[aBase + (kt) + 16 * DM],  &Ah[B][ldsw + 512]);   \
    gl16(&Xl[aBase + (kt)],            &Al[B][ldsw]);         \
    gl16(&Xl[aBase + (kt) + 16 * DM],  &Al[B][ldsw + 512]);   \
  } while (0)
#define LOADB(dh, dl, kt) do {                                \
    _Pragma("unroll")                                         \
    for (int n = 0; n < 2; ++n) {                             \
      dh[n] = *(const bf8*)&Wfh[bB[n] + (size_t)(kt) * 512];  \
      dl[n] = *(const bf8*)&Wfl[bB[n] + (size_t)(kt) * 512];  \
    }                                                         \
  } while (0)
// read A frags for rows [h0*16 .. h0*16+64) and run their MFMAs
#define QKHALF(B, h0, bh, bl) do {                            \
    bf8 ah[4], al4[4];                                        \
    _Pragma("unroll")                                         \
    for (int mm = 0; mm < 4; ++mm) {                          \
      int ro = (((h0) + mm) * 16 + c) * 32 + rsw;             \
      ah[mm]  = *(const bf8*)&Ah[B][ro];                      \
      al4[mm] = *(const bf8*)&Al[B][ro];                      \
    }                                                         \
    __builtin_amdgcn_s_setprio(1);                            \
    _Pragma("unroll")                                         \
    for (int mm = 0; mm < 4; ++mm) {                          \
      _Pragma("unroll")                                       \
      for (int n = 0; n < 2; ++n) {                           \
        acc[(h0) + mm][n] = __builtin_amdgcn_mfma_f32_16x16x32_bf16(al4[mm], bh[n], acc[(h0) + mm][n], 0, 0, 0); \
        acc[(h0) + mm][n] = __builtin_amdgcn_mfma_f32_16x16x32_bf16(ah[mm], bl[n], acc[(h0) + mm][n], 0, 0, 0);  \
        acc[(h0) + mm][n] = __builtin_amdgcn_mfma_f32_16x16x32_bf16(ah[mm], bh[n], acc[(h0) + mm][n], 0, 0, 0);  \
      }                                                       \
    }                                                         \
    __builtin_amdgcn_s_setprio(0);                            \
  } while (0)

    bf8 b0h[2], b0l[2], b1h[2], b1l[2];
    LOADB(b0h, b0l, 0);
    ASTAGE(0, 0);
    __syncthreads();

    for (int it = 0; it < 32; it += 2) {
      LOADB(b1h, b1l, it + 1);
      ASTAGE(1, (it + 1) * 32);
      QKHALF(0, 0, b0h, b0l);
      QKHALF(0, 4, b0h, b0l);
      __syncthreads();

      if (it + 2 < 32) {
        LOADB(b0h, b0l, it + 2);
        ASTAGE(0, (it + 2) * 32);
      }
      QKHALF(1, 0, b1h, b1l);
      QKHALF(1, 4, b1h, b1l);
      __syncthreads();
    }
#undef ASTAGE
#undef LOADB
#undef QKHALF

#pragma unroll
    for (int m = 0; m < 8; ++m)
#pragma unroll
      for (int n = 0; n < 2; ++n)
#pragma unroll
        for (int j = 0; j < 4; ++j) {
          int grow = rowBase + m * 16 + g * 4 + j;             // 0..4095
          int gcol = colBase + w * 32 + n * 16 + c;            // 0..2047
          int h = (gcol >> 6) & 15, e = gcol & 63;
          int bb = grow >> 11, s = grow & 2047;
          size_t hb = (size_t)(bb * NH + h);
          if (gcol < 1024) {                 // Q: orig col h*192+e
            float q8 = (acc[m][n][j] + bias[h * 192 + e]) * QSCALE;
            short hi = f2bf(q8);
            short lo = f2bf(q8 - bf2f(hi));
            size_t idx = (hb * S_LEN + s) * DH + e;
            Qh[idx] = hi; Ql[idx] = lo;
          } else {                           // K: orig col h*192+64+e
            float v = acc[m][n][j] + bias[h * 192 + 64 + e];
            short hi = f2bf(v);
            short lo = f2bf(v - bf2f(hi));
            int tile = s >> 6, r = s & 63;
            size_t idx = ((hb * NT + tile) * (size_t)4096) + r * 64 +
                         ((((e >> 3) ^ (r & 7)) << 3) | (e & 7));
            Kh[idx] = hi; Kl[idx] = lo;
          }
        }
  } else {
    // ---------------- V path (1-pass) ----------------
    const int id = blockIdx.x - 512;            // 0..255
    const int t = id >> 3;                      // 0..31
    const int rowBase = (((id & 7) << 2) + (t & 3)) * 128;
    const int colBase = 2048 + (t >> 2) * 128;  // permuted V region

    f32x4 acc[8][2] = {};
    const size_t aBase = (size_t)(rowBase + sr) * DM + csw;

    size_t bB[2];
#pragma unroll
    for (int n = 0; n < 2; ++n)
      bB[n] = ((size_t)((colBase >> 4) + w * 2 + n) * 32) * 512 + lane * 8;

#define VASTAGE(B, kt) do {                                   \
    gl16(&Xh[aBase + (kt)],            &Ah[B][ldsw]);         \
    gl16(&Xh[aBase + (kt) + 16 * DM],  &Ah[B][ldsw + 512]);   \
  } while (0)
#define VLOADB(dh, kt) do {                                   \
    _Pragma("unroll")                                         \
    for (int n = 0; n < 2; ++n)                               \
      dh[n] = *(const bf8*)&Wfh[bB[n] + (size_t)(kt) * 512];  \
  } while (0)
#define VHALF(B, h0, bh) do {                                 \
    bf8 ah[4];                                                \
    _Pragma("unroll")                                         \
    for (int mm = 0; mm < 4; ++mm)                            \
      ah[mm] = *(const bf8*)&Ah[B][(((h0) + mm) * 16 + c) * 32 + rsw]; \
    __builtin_amdgcn_s_setprio(1);                            \
    _Pragma("unroll")                                         \
    for (int mm = 0; mm < 4; ++mm) {                          \
      _Pragma("unroll")                                       \
      for (int n = 0; n < 2; ++n)                             \
        acc[(h0) + mm][n] = __builtin_amdgcn_mfma_f32_16x16x32_bf16(ah[mm], bh[n], acc[(h0) + mm][n], 0, 0, 0); \
    }                                                         \
    __builtin_amdgcn_s_setprio(0);                            \
  } while (0)

    bf8 b0h[2], b1h[2];
    VLOADB(b0h, 0);
    VASTAGE(0, 0);
    __syncthreads();

    for (int it = 0; it < 32; it += 2) {
      VLOADB(b1h, it + 1);
      VASTAGE(1, (it + 1) * 32);
      VHALF(0, 0, b0h);
      VHALF(0, 4, b0h);
      __syncthreads();

      if (it + 2 < 32) {
        VLOADB(b0h, it + 2);
        VASTAGE(0, (it + 2) * 32);
      }
      VHALF(1, 0, b1h);
      VHALF(1, 4, b1h);
      __syncthreads();
    }
#undef VASTAGE
#undef VLOADB
#undef VHALF

    // epilogue: V -> [bh][tile][d][key-permuted], chunk-XOR-swizzled by d&7
#pragma unroll
    for (int m = 0; m < 8; ++m)
#pragma unroll
      for (int n = 0; n < 2; ++n)
#pragma unroll
        for (int j = 0; j < 4; ++j) {
          int grow = rowBase + m * 16 + g * 4 + j;
          int gcol = colBase + w * 32 + n * 16 + c;          // 2048..3071
          int h = (gcol >> 6) & 15, d = gcol & 63;
          int bb = grow >> 11, s = grow & 2047;
          size_t hb = (size_t)(bb * NH + h);
          float v = acc[m][n][j] + bias[h * 192 + 128 + d];
          int tile = s >> 6, key = s & 63;
          int kc = key >> 5, g4 = (key >> 2) & 3;
          int ii = (((key >> 4) & 1) << 2) | (key & 3);
          size_t idx = ((hb * NT + tile) * (size_t)4096) + d * 64 +
                       (((((kc << 2) | g4) ^ (d & 7)) << 3) | ii);
          Vt[idx] = f2bf(v);
        }
  }
}

// ------------------------------ attention -----------------------------------
// v10 verbatim: 512 blocks (XCD-swizzled), 8 waves x 16 q-rows share one bh.
// Swapped QK^T with -mrun folded into the MFMA C-init; in-lane max; lsum via
// MFMA ones-column; cvt_pk P-pack. K/V LDS-dbuf via global_load_lds, ONE
// barrier per tile.
__global__ __launch_bounds__(512, 4) void attn(
    const short* __restrict__ Qh, const short* __restrict__ Ql,
    const short* __restrict__ KhG, const short* __restrict__ KlG,
    const short* __restrict__ VtG, float* __restrict__ out) {
  __shared__ short KHs[2][4096];   // 16 KB
  __shared__ short KLs[2][4096];   // 16 KB
  __shared__ short Vs[2][4096];    // 16 KB

  const int tid = threadIdx.x;
  const int lane = tid & 63, w = tid >> 6;     // 8 waves
  const int c = lane & 15, g = lane >> 4;
  const int id = blockIdx.x;                   // 0..511
  const int lid = (id & 7) * 64 + (id >> 3);   // 64 consecutive per XCD
  const int bh = lid >> 4;
  const int q0 = (lid & 15) * 128 + w * 16;
  const size_t qBase  = (size_t)bh * S_LEN * DH;
  const size_t kvBase = (size_t)bh * NT * 4096;

  const int seg = tid * 8;     // one 16B chunk per thread per buffer

  // q fragments (hi/lo), rows q0+c — used as the MFMA B operand
  bf8 qh[2], ql[2];
#pragma unroll
  for (int kc = 0; kc < 2; ++kc) {
    size_t idx = qBase + (size_t)(q0 + c) * DH + kc * 32 + g * 8;
    qh[kc] = *(const bf8*)&Qh[idx];
    ql[kc] = *(const bf8*)&Ql[idx];
  }

  // t-invariant swizzled fragment offsets ((i*16+c)&7 == c&7)
  int koff[2][4];
#pragma unroll
  for (int kc = 0; kc < 2; ++kc)
#pragma unroll
    for (int i = 0; i < 4; ++i)
      koff[kc][i] = (i * 16 + c) * 64 + (((kc * 4 + g) ^ (c & 7)) << 3);

  f32x4 mneg = {0.f, 0.f, 0.f, 0.f};   // all elems = -mrun (q-row c)
  f32x4 osum = {};                     // osum[j] = lsum of q-row 4g+j
  f32x4 o[4] = {};                     // o[db][j]: row 4g+j, d = db*16+c
  union { bf8 v; unsigned u[4]; } ones;
  ones.u[0] = ones.u[1] = ones.u[2] = ones.u[3] = 0x3F803F80u;  // bf16 1.0 x8

  // prologue: stage tile 0
  gl16(&KhG[kvBase + seg], &KHs[0][seg]);
  gl16(&KlG[kvBase + seg], &KLs[0][seg]);
  gl16(&VtG[kvBase + seg], &Vs[0][seg]);
  __syncthreads();

  for (int t = 0; t < NT; ++t) {
    const int cur = t & 1, nxt = cur ^ 1;
    if (t + 1 < NT) {                    // DMA next tile; lands under compute
      size_t tb = kvBase + (size_t)(t + 1) * 4096 + seg;
      gl16(&KhG[tb], &KHs[nxt][seg]);
      gl16(&KlG[tb], &KLs[nxt][seg]);
      gl16(&VtG[tb], &Vs[nxt][seg]);
    }
    const short* KH = &KHs[cur][0];
    const short* KL = &KLs[cur][0];
    const short* VV = &Vs[cur][0];

    // scores, swapped: sc[nb][j] = S[key=16nb+4g+j][q-row c] - mrun
    f32x4 sc[4];
    __builtin_amdgcn_s_setprio(1);
#pragma unroll
    for (int nb = 0; nb < 4; ++nb) {
      bf8 kh0 = *(const bf8*)&KH[koff[0][nb]];
      bf8 kl0 = *(const bf8*)&KL[koff[0][nb]];
      f32x4 s = __builtin_amdgcn_mfma_f32_16x16x32_bf16(kh0, ql[0], mneg, 0, 0, 0);
      s = __builtin_amdgcn_mfma_f32_16x16x32_bf16(kl0, qh[0], s, 0, 0, 0);
      s = __builtin_amdgcn_mfma_f32_16x16x32_bf16(kh0, qh[0], s, 0, 0, 0);
      bf8 kh1 = *(const bf8*)&KH[koff[1][nb]];
      bf8 kl1 = *(const bf8*)&KL[koff[1][nb]];
      s = __builtin_amdgcn_mfma_f32_16x16x32_bf16(kh1, ql[1], s, 0, 0, 0);
      s = __builtin_amdgcn_mfma_f32_16x16x32_bf16(kl1, qh[1], s, 0, 0, 0);
      s = __builtin_amdgcn_mfma_f32_16x16x32_bf16(kh1, qh[1], s, 0, 0, 0);
      sc[nb] = s;
    }
    __builtin_amdgcn_s_setprio(0);

    // in-lane row max, then across the 4 g-copies
    float m0 = fmaxf(fmaxf(sc[0][0], sc[0][1]), sc[0][2]);
    m0 = fmaxf(fmaxf(m0, sc[0][3]), sc[1][0]);
    m0 = fmaxf(fmaxf(m0, sc[1][1]), sc[1][2]);
    m0 = fmaxf(fmaxf(m0, sc[1][3]), sc[2][0]);
    m0 = fmaxf(fmaxf(m0, sc[2][1]), sc[2][2]);
    m0 = fmaxf(fmaxf(m0, sc[2][3]), sc[3][0]);
    m0 = fmaxf(fmaxf(m0, sc[3][1]), sc[3][2]);
    m0 = fmaxf(m0, sc[3][3]);
    m0 = fmaxf(m0, __shfl_xor(m0, 16));
    m0 = fmaxf(m0, __shfl_xor(m0, 32));

    if (__any(m0 > 8.0f)) {              // defer-max: p bounded by 2^8
      float delta = fmaxf(m0, 0.0f);
      float scale = exp2f(-delta);
      int sb = (g << 4) | (g << 2);
      float s0 = __shfl(scale, sb);
      float s1 = __shfl(scale, sb + 1);
      float s2 = __shfl(scale, sb + 2);
      float s3 = __shfl(scale, sb + 3);
#pragma unroll
      for (int db = 0; db < 4; ++db) {
        o[db][0] *= s0; o[db][1] *= s1; o[db][2] *= s2; o[db][3] *= s3;
      }
      osum[0] *= s0; osum[1] *= s1; osum[2] *= s2; osum[3] *= s3;
      mneg[0] -= delta; mneg[1] -= delta; mneg[2] -= delta; mneg[3] -= delta;
#pragma unroll
      for (int nb = 0; nb < 4; ++nb)
#pragma unroll
        for (int j = 0; j < 4; ++j)
          sc[nb][j] = exp2f(sc[nb][j] - delta);
    } else {
#pragma unroll
      for (int nb = 0; nb < 4; ++nb)
#pragma unroll
        for (int j = 0; j < 4; ++j)
          sc[nb][j] = exp2f(sc[nb][j]);
    }

    // pack p into PV A-fragments (cvt_pk)
    union { bf8 v; unsigned u[4]; } pa[2];
#pragma unroll
    for (int kc = 0; kc < 2; ++kc) {
      asm("v_cvt_pk_bf16_f32 %0, %1, %2"
          : "=v"(pa[kc].u[0]) : "v"(sc[2 * kc][0]), "v"(sc[2 * kc][1]));
      asm("v_cvt_pk_bf16_f32 %0, %1, %2"
          : "=v"(pa[kc].u[1]) : "v"(sc[2 * kc][2]), "v"(sc[2 * kc][3]));
      asm("v_cvt_pk_bf16_f32 %0, %1, %2"
          : "=v"(pa[kc].u[2]) : "v"(sc[2 * kc + 1][0]), "v"(sc[2 * kc + 1][1]));
      asm("v_cvt_pk_bf16_f32 %0, %1, %2"
          : "=v"(pa[kc].u[3]) : "v"(sc[2 * kc + 1][2]), "v"(sc[2 * kc + 1][3]));
    }

    // PV + lsum: B = V fragment (key-permuted) and ones column
    __builtin_amdgcn_s_setprio(1);
#pragma unroll
    for (int kc = 0; kc < 2; ++kc) {
      osum = __builtin_amdgcn_mfma_f32_16x16x32_bf16(pa[kc].v, ones.v, osum, 0, 0, 0);
#pragma unroll
      for (int db = 0; db < 4; ++db) {
        bf8 vb = *(const bf8*)&VV[koff[kc][db]];
        o[db] = __builtin_amdgcn_mfma_f32_16x16x32_bf16(pa[kc].v, vb, o[db], 0, 0, 0);
      }
    }
    __builtin_amdgcn_s_setprio(0);

    __syncthreads();   // drains vmcnt (next tile staged) + cur reads done
  }

  // final: lsum is lane-local in osum[j]
  float r0 = 1.f / osum[0];
  float r1 = 1.f / osum[1];
  float r2 = 1.f / osum[2];
  float r3 = 1.f / osum[3];

  const int b = bh >> 4, h = bh & 15;
#pragma unroll
  for (int db = 0; db < 4; ++db) {
    int col = h * DH + db * 16 + c;
    out[((size_t)b * S_LEN + q0 + g * 4 + 0) * DM + col] = o[db][0] * r0;
    out[((size_t)b * S_LEN + q0 + g * 4 + 1) * DM + col] = o[db][1] * r1;
    out[((size_t)b * S_LEN + q0 + g * 4 + 2) * DM + col] = o[db][2] * r2;
    out[((size_t)b * S_LEN + q0 + g * 4 + 3) * DM + col] = o[db][3] * r3;
  }
}

// ---------------------------------------------------------------------------
extern "C" void kernel_launch(void* const* d_in, const int* in_sizes, int n_in,
                              void* d_out, int out_size, void* d_ws, size_t ws_size,
                              hipStream_t stream) {
  const float* X    = (const float*)d_in[0];
  const float* W    = (const float*)d_in[1];
  const float* bias = (const float*)d_in[2];
  float* out = (float*)d_out;

  char* ws = (char*)d_ws;
  size_t off = 0;
  auto take = [&](size_t bytes) {
    void* p = ws + off;
    off += (bytes + 255) & ~(size_t)255;
    return p;
  };
  short* Xh  = (short*)take((size_t)NROWS * DM * 2);   // 8.4 MB
  short* Xl  = (short*)take((size_t)NROWS * DM * 2);
  short* Wfh = (short*)take((size_t)EW * DM * 2);      // 6.3 MB
  short* Wfl = (short*)take((size_t)EW * DM * 2);
  short* Qh  = (short*)take((size_t)2 * NH * S_LEN * DH * 2);  // 8.4 MB each
  short* Ql  = (short*)take((size_t)2 * NH * S_LEN * DH * 2);
  short* Kh  = (short*)take((size_t)2 * NH * NT * 4096 * 2);
  short* Kl  = (short*)take((size_t)2 * NH * NT * 4096 * 2);
  short* Vt  = (short*)take((size_t)2 * NH * NT * 4096 * 2);
  // total ~71.3 MB of workspace

  prep<<<dim3(4096 + 3072), dim3(256), 0, stream>>>(X, W, Xh, Xl, Wfh, Wfl);
  proj<<<dim3(768), dim3(256), 0, stream>>>(
      Xh, Xl, Wfh, Wfl, bias, Qh, Ql, Kh, Kl, Vt);
  attn<<<dim3(512), dim3(512), 0, stream>>>(
      Qh, Ql, Kh, Kl, Vt, out);
}